// Round 11
// baseline (194.191 us; speedup 1.0000x reference)
//
#include <hip/hip_runtime.h>
#include <hip/hip_fp16.h>

#define NN 50000
#define NE 800000
#define DD 64
#define NG 64

#define NBKT 196        // ceil(NN/256) coarse buckets (dst >> 8)
#define MAXB 5120       // padded tmp slots per bucket (mean 4082)
#define SRTB 7168       // srt slots per bucket (>= MAXB + 256*7 pad worst case)
#define P1CH 4096       // edges per pass-1 block
#define P1NB ((NE + P1CH - 1) / P1CH)   // 196

// ---------------- pass 1: bin edges by dst>>8 into padded tmp buckets ----------------
__global__ __launch_bounds__(256) void bin_k(const int* __restrict__ ei,
                                             const float* __restrict__ ew,
                                             int* __restrict__ bucket_cnt,
                                             unsigned int* __restrict__ tmp_pay,
                                             unsigned char* __restrict__ tmp_c8) {
    __shared__ int hist[NBKT];
    __shared__ int basec[NBKT];
    const int t = threadIdx.x;
    const int e0 = blockIdx.x * P1CH;
    for (int i = t; i < NBKT; i += 256) hist[i] = 0;
    __syncthreads();
    int rr[16]; int cc[16]; float wwf[16];
    #pragma unroll
    for (int i = 0; i < 16; ++i) {
        int e = e0 + i * 256 + t;
        if (e < NE) {
            rr[i] = ei[e]; cc[i] = ei[NE + e]; wwf[i] = ew[e];
            atomicAdd(&hist[cc[i] >> 8], 1);
        } else cc[i] = -1;
    }
    __syncthreads();
    for (int i = t; i < NBKT; i += 256)
        basec[i] = (hist[i] > 0) ? (i * MAXB + atomicAdd(&bucket_cnt[i], hist[i])) : 0;
    __syncthreads();
    #pragma unroll
    for (int i = 0; i < 16; ++i) {
        if (cc[i] >= 0) {
            int b = cc[i] >> 8;
            int slot = atomicAdd(&basec[b], 1);   // LDS cursor within reservation
            unsigned int hb = (unsigned int)__half_as_ushort(__float2half(wwf[i]));
            tmp_pay[slot] = (hb << 16) | (unsigned int)rr[i];
            tmp_c8[slot] = (unsigned char)(cc[i] & 255);
        }
    }
}

// ---------------- pass 2: per-bucket exact sort + per-node (start,pcnt) + dis ----------
__global__ __launch_bounds__(256) void build_k(const int* __restrict__ bucket_cnt,
                                               const unsigned int* __restrict__ tmp_pay,
                                               const unsigned char* __restrict__ tmp_c8,
                                               unsigned int* __restrict__ srt,
                                               int2* __restrict__ rowse,
                                               float* __restrict__ dis) {
    __shared__ int hist[256];
    __shared__ int cursor[256];
    __shared__ float degf[256];
    __shared__ int wtot[4];
    const int b = blockIdx.x;
    const int t = threadIdx.x;
    const int cntb = bucket_cnt[b];
    const int tbase = b * MAXB;
    hist[t] = 0; degf[t] = 0.0f;
    __syncthreads();
    for (int i = t; i < cntb; i += 256) atomicAdd(&hist[tmp_c8[tbase + i]], 1);
    __syncthreads();
    const int v = hist[t];
    const int pv = (v + 7) & ~7;
    int pre = pv;
    #pragma unroll
    for (int off = 1; off < 64; off <<= 1) {
        int u = __shfl_up(pre, off);
        if ((t & 63) >= off) pre += u;
    }
    if ((t & 63) == 63) wtot[t >> 6] = pre;
    __syncthreads();
    int woff = 0;
    for (int i = 0; i < (t >> 6); ++i) woff += wtot[i];
    const int start = b * SRTB + woff + pre - pv;
    cursor[t] = start;
    __syncthreads();
    for (int i = t; i < cntb; i += 256) {
        unsigned int u = tmp_pay[tbase + i];
        int c8 = tmp_c8[tbase + i];
        int slot = atomicAdd(&cursor[c8], 1);   // LDS
        srt[slot] = u;
        float w = __half2float(__ushort_as_half((unsigned short)(u >> 16)));
        atomicAdd(&degf[c8], w);                // LDS fp32
    }
    __syncthreads();
    for (int i = start + v; i < start + pv; ++i) srt[i] = 0u;
    const int node = b * 256 + t;
    if (node < NN) {
        rowse[node] = make_int2(start, pv);
        dis[node] = rsqrtf(1.0f + degf[t]);
    }
}

// ---------------- GEMM: A' = (act(X) @ W) * dis[row], fp16 out, feature-sliced ------
template<bool ACT>
__global__ __launch_bounds__(256) void gemm_k(
    const float* __restrict__ X, const float* __restrict__ W,
    const float* __restrict__ bias_prev, const float* __restrict__ dis,
    __half* __restrict__ Alo, __half* __restrict__ Ahi)
{
    __shared__ float Ws[64][64];
    __shared__ float Xt[64][68];   // transposed, padded for float4 alignment
    const int t = threadIdx.x;
    const int row0 = blockIdx.x * 64;

    #pragma unroll
    for (int s = t; s < 64 * 64; s += 256) Ws[s >> 6][s & 63] = W[s];
    #pragma unroll
    for (int s = t; s < 64 * 64; s += 256) {
        int r = s >> 6, k = s & 63;
        int row = row0 + r;
        if (row >= NN) row = NN - 1;
        float v = X[(size_t)row * DD + k];
        if (ACT) v = fmaxf(v + bias_prev[k], 0.0f);
        Xt[k][r] = v;
    }
    __syncthreads();

    const int tc = t & 15;
    const int tr = t >> 4;
    float acc[4][4];
    #pragma unroll
    for (int i = 0; i < 4; ++i)
        #pragma unroll
        for (int j = 0; j < 4; ++j) acc[i][j] = 0.0f;

    const float4* xp = (const float4*)&Xt[0][tr * 4];
    const float4* wp = (const float4*)&Ws[0][tc * 4];
    #pragma unroll
    for (int k = 0; k < 64; ++k) {
        float4 xv = xp[k * 17];
        float4 wv = wp[k * 16];
        acc[0][0] += xv.x * wv.x; acc[0][1] += xv.x * wv.y; acc[0][2] += xv.x * wv.z; acc[0][3] += xv.x * wv.w;
        acc[1][0] += xv.y * wv.x; acc[1][1] += xv.y * wv.y; acc[1][2] += xv.y * wv.z; acc[1][3] += xv.y * wv.w;
        acc[2][0] += xv.z * wv.x; acc[2][1] += xv.z * wv.y; acc[2][2] += xv.z * wv.z; acc[2][3] += xv.z * wv.w;
        acc[3][0] += xv.w * wv.x; acc[3][1] += xv.w * wv.y; acc[3][2] += xv.w * wv.z; acc[3][3] += xv.w * wv.w;
    }

    __half* base = (tc < 8) ? Alo : Ahi;
    const int fo = (tc < 8) ? tc * 4 : (tc - 8) * 4;
    #pragma unroll
    for (int i = 0; i < 4; ++i) {
        int row = row0 + tr * 4 + i;
        if (row >= NN) break;
        float d = dis[row];
        __half2 h0 = __floats2half2_rn(acc[i][0] * d, acc[i][1] * d);
        __half2 h1 = __floats2half2_rn(acc[i][2] * d, acc[i][3] * d);
        uint2 st;
        st.x = *reinterpret_cast<unsigned int*>(&h0);
        st.y = *reinterpret_cast<unsigned int*>(&h1);
        *reinterpret_cast<uint2*>(&base[(size_t)row * 32 + fo]) = st;
    }
}

// ---------------- gather (one 32-feature slice): B[c,s] = dis*(A'[c]+sum w*A'[r]) ----
// Half-wave (32 lanes) per node: 64 B row loads from the L2-resident slice;
// 8 independent row loads in flight per half-wave (16 per wave).
__global__ __launch_bounds__(256) void gather_k(
    const int2* __restrict__ rowse, const unsigned int* __restrict__ srt,
    const float* __restrict__ dis,
    const __half* __restrict__ As,      // [NN][32] slice
    float* __restrict__ B)              // [NN][64], slice offset pre-applied
{
    const int node = blockIdx.x * 8 + (threadIdx.x >> 5);
    const int l = threadIdx.x & 31;
    if (node >= NN) return;
    const int2 se = rowse[node];
    float acc0 = __half2float(As[(size_t)node * 32 + l]);  // self-loop term
    float acc1 = 0.0f, acc2 = 0.0f, acc3 = 0.0f;
    const unsigned int* p = srt + se.x;
    uint4 u0 = *reinterpret_cast<const uint4*>(p);
    uint4 u1 = *reinterpret_cast<const uint4*>(p + 4);
    for (int n = se.y; n > 0; n -= 8) {
        uint4 n0, n1;
        if (n > 8) {
            p += 8;
            n0 = *reinterpret_cast<const uint4*>(p);
            n1 = *reinterpret_cast<const uint4*>(p + 4);
        }
        __half h0 = As[(size_t)(u0.x & 0xffffu) * 32 + l];
        __half h1 = As[(size_t)(u0.y & 0xffffu) * 32 + l];
        __half h2 = As[(size_t)(u0.z & 0xffffu) * 32 + l];
        __half h3 = As[(size_t)(u0.w & 0xffffu) * 32 + l];
        __half h4 = As[(size_t)(u1.x & 0xffffu) * 32 + l];
        __half h5 = As[(size_t)(u1.y & 0xffffu) * 32 + l];
        __half h6 = As[(size_t)(u1.z & 0xffffu) * 32 + l];
        __half h7 = As[(size_t)(u1.w & 0xffffu) * 32 + l];
        acc0 += __half2float(__ushort_as_half((unsigned short)(u0.x >> 16))) * __half2float(h0);
        acc1 += __half2float(__ushort_as_half((unsigned short)(u0.y >> 16))) * __half2float(h1);
        acc2 += __half2float(__ushort_as_half((unsigned short)(u0.z >> 16))) * __half2float(h2);
        acc3 += __half2float(__ushort_as_half((unsigned short)(u0.w >> 16))) * __half2float(h3);
        acc0 += __half2float(__ushort_as_half((unsigned short)(u1.x >> 16))) * __half2float(h4);
        acc1 += __half2float(__ushort_as_half((unsigned short)(u1.y >> 16))) * __half2float(h5);
        acc2 += __half2float(__ushort_as_half((unsigned short)(u1.z >> 16))) * __half2float(h6);
        acc3 += __half2float(__ushort_as_half((unsigned short)(u1.w >> 16))) * __half2float(h7);
        u0 = n0; u1 = n1;
    }
    float r = dis[node] * ((acc0 + acc1) + (acc2 + acc3));
    __builtin_nontemporal_store(r, &B[(size_t)node * DD + l]);
}

// ---------------- pooling: 32 rows per block ----------------
__global__ __launch_bounds__(64) void pool(
    const float* __restrict__ B, const float* __restrict__ b2,
    const int* __restrict__ batch,
    float* __restrict__ sums, float* __restrict__ cnts, int n)
{
    const int lane = threadIdx.x;
    const int start = blockIdx.x * 32;
    const int end = min(start + 32, n);
    const float bb = b2[lane];
    float acc = 0.0f;
    int cn = 0;
    int curg = batch[start];
    for (int i = start; i < end; ++i) {
        int g = batch[i];
        if (g != curg) {
            unsafeAtomicAdd(&sums[curg * DD + lane], acc);
            if (lane == 0) unsafeAtomicAdd(&cnts[curg], (float)cn);
            acc = 0.0f; cn = 0; curg = g;
        }
        acc += fmaxf(B[(size_t)i * DD + lane] + bb, 0.0f);
        cn++;
    }
    if (cn > 0) {
        unsafeAtomicAdd(&sums[curg * DD + lane], acc);
        if (lane == 0) unsafeAtomicAdd(&cnts[curg], (float)cn);
    }
}

__global__ void finalize(const float* __restrict__ sums, const float* __restrict__ cnts,
                         float* __restrict__ out) {
    int i = blockIdx.x * blockDim.x + threadIdx.x;
    if (i < NG * DD) {
        int g = i >> 6;
        out[i] = sums[i] / fmaxf(cnts[g], 1.0f);
    }
}

// ---------------- host ----------------
extern "C" void kernel_launch(void* const* d_in, const int* in_sizes, int n_in,
                              void* d_out, int out_size, void* d_ws, size_t ws_size,
                              hipStream_t stream) {
    const float* x   = (const float*)d_in[0];
    const int*   ei  = (const int*)  d_in[1];
    const float* ew  = (const float*)d_in[2];
    const int*   bat = (const int*)  d_in[3];
    const float* W1  = (const float*)d_in[4];
    const float* b1  = (const float*)d_in[5];
    const float* W2  = (const float*)d_in[6];
    const float* b2  = (const float*)d_in[7];
    float* out = (float*)d_out;

    char* ws = (char*)d_ws;
    size_t off = 0;
    __half* Alo       = (__half*)(ws + off); off += (size_t)NN * 32 * 2;          // 3.2 MB
    __half* Ahi       = (__half*)(ws + off); off += (size_t)NN * 32 * 2;          // 3.2 MB
    float*  B         = (float*) (ws + off); off += (size_t)NN * DD * 4;          // 12.8 MB
    unsigned int* srt = (unsigned int*)(ws + off); off += (size_t)NBKT * SRTB * 4; // 5.6 MB
    unsigned int* tmp_pay = (unsigned int*)(ws + off); off += (size_t)NBKT * MAXB * 4;  // 4.0 MB
    unsigned char* tmp_c8 = (unsigned char*)(ws + off); off += (size_t)NBKT * MAXB;     // 1.0 MB
    int2*   rowse      = (int2*)(ws + off); off += (size_t)NN * 8;
    float*  dis        = (float*)(ws + off); off += (size_t)NN * 4;
    // contiguous zero-init region: bucket_cnt | sums | cnts
    int*    bucket_cnt = (int*)  (ws + off); off += (size_t)NBKT * 4;
    float*  sums       = (float*)(ws + off); off += (size_t)NG * DD * 4;
    float*  cnts       = (float*)(ws + off); off += (size_t)NG * 4;

    (void)hipMemsetAsync(bucket_cnt, 0, (size_t)(NBKT + NG * DD + NG) * 4, stream);

    // CSR build (shared by both layers) — no per-edge global atomics
    bin_k<<<P1NB, 256, 0, stream>>>(ei, ew, bucket_cnt, tmp_pay, tmp_c8);
    build_k<<<NBKT, 256, 0, stream>>>(bucket_cnt, tmp_pay, tmp_c8, srt, rowse, dis);

    const int GG = (NN + 7) / 8;   // 6250 blocks per gather slice pass

    // layer 1
    gemm_k<false><<<(NN + 63) / 64, 256, 0, stream>>>(x, W1, nullptr, dis, Alo, Ahi);
    gather_k<<<GG, 256, 0, stream>>>(rowse, srt, dis, Alo, B);
    gather_k<<<GG, 256, 0, stream>>>(rowse, srt, dis, Ahi, B + 32);

    // layer 2
    gemm_k<true><<<(NN + 63) / 64, 256, 0, stream>>>(B, W2, b1, dis, Alo, Ahi);
    gather_k<<<GG, 256, 0, stream>>>(rowse, srt, dis, Alo, B);
    gather_k<<<GG, 256, 0, stream>>>(rowse, srt, dis, Ahi, B + 32);

    // pooling (bias+relu fused on read)
    pool<<<(NN + 31) / 32, 64, 0, stream>>>(B, b2, bat, sums, cnts, NN);
    finalize<<<(NG * DD + 255) / 256, 256, 0, stream>>>(sums, cnts, out);
}

// Round 12
// 142.339 us; speedup vs baseline: 1.3643x; 1.3643x over previous
//
#include <hip/hip_runtime.h>
#include <hip/hip_fp16.h>

#define NN 50000
#define NE 800000
#define DD 64
#define NG 64

#define NBKT 196        // ceil(NN/256) coarse buckets (dst >> 8)
#define MAXB 5120       // padded tmp slots per bucket (mean 4082)
#define SRTB 7168       // srt slots per bucket (>= MAXB + 256*7 pad worst case)
#define P1CH 4096       // edges per pass-1 block
#define P1NB ((NE + P1CH - 1) / P1CH)   // 196

// ---------------- pass 1: bin edges by dst>>8 into padded tmp buckets ----------------
__global__ __launch_bounds__(256) void bin_k(const int* __restrict__ ei,
                                             const float* __restrict__ ew,
                                             int* __restrict__ bucket_cnt,
                                             unsigned int* __restrict__ tmp_pay,
                                             unsigned char* __restrict__ tmp_c8) {
    __shared__ int hist[NBKT];
    __shared__ int basec[NBKT];
    const int t = threadIdx.x;
    const int e0 = blockIdx.x * P1CH;
    for (int i = t; i < NBKT; i += 256) hist[i] = 0;
    __syncthreads();
    int rr[16]; int cc[16]; float wwf[16];
    #pragma unroll
    for (int i = 0; i < 16; ++i) {
        int e = e0 + i * 256 + t;
        if (e < NE) {
            rr[i] = ei[e]; cc[i] = ei[NE + e]; wwf[i] = ew[e];
            atomicAdd(&hist[cc[i] >> 8], 1);
        } else cc[i] = -1;
    }
    __syncthreads();
    for (int i = t; i < NBKT; i += 256)
        basec[i] = (hist[i] > 0) ? (i * MAXB + atomicAdd(&bucket_cnt[i], hist[i])) : 0;
    __syncthreads();
    #pragma unroll
    for (int i = 0; i < 16; ++i) {
        if (cc[i] >= 0) {
            int b = cc[i] >> 8;
            int slot = atomicAdd(&basec[b], 1);   // LDS cursor within reservation
            unsigned int hb = (unsigned int)__half_as_ushort(__float2half(wwf[i]));
            tmp_pay[slot] = (hb << 16) | (unsigned int)rr[i];
            tmp_c8[slot] = (unsigned char)(cc[i] & 255);
        }
    }
}

// ---------------- pass 2: per-bucket exact sort + per-node (start,pcnt) + dis ----------
__global__ __launch_bounds__(256) void build_k(const int* __restrict__ bucket_cnt,
                                               const unsigned int* __restrict__ tmp_pay,
                                               const unsigned char* __restrict__ tmp_c8,
                                               unsigned int* __restrict__ srt,
                                               int2* __restrict__ rowse,
                                               float* __restrict__ dis) {
    __shared__ int hist[256];
    __shared__ int cursor[256];
    __shared__ float degf[256];
    __shared__ int wtot[4];
    const int b = blockIdx.x;
    const int t = threadIdx.x;
    const int cntb = bucket_cnt[b];
    const int tbase = b * MAXB;
    hist[t] = 0; degf[t] = 0.0f;
    __syncthreads();
    for (int i = t; i < cntb; i += 256) atomicAdd(&hist[tmp_c8[tbase + i]], 1);
    __syncthreads();
    const int v = hist[t];
    const int pv = (v + 7) & ~7;
    int pre = pv;
    #pragma unroll
    for (int off = 1; off < 64; off <<= 1) {
        int u = __shfl_up(pre, off);
        if ((t & 63) >= off) pre += u;
    }
    if ((t & 63) == 63) wtot[t >> 6] = pre;
    __syncthreads();
    int woff = 0;
    for (int i = 0; i < (t >> 6); ++i) woff += wtot[i];
    const int start = b * SRTB + woff + pre - pv;
    cursor[t] = start;
    __syncthreads();
    for (int i = t; i < cntb; i += 256) {
        unsigned int u = tmp_pay[tbase + i];
        int c8 = tmp_c8[tbase + i];
        int slot = atomicAdd(&cursor[c8], 1);   // LDS
        srt[slot] = u;
        float w = __half2float(__ushort_as_half((unsigned short)(u >> 16)));
        atomicAdd(&degf[c8], w);                // LDS fp32
    }
    __syncthreads();
    for (int i = start + v; i < start + pv; ++i) srt[i] = 0u;
    const int node = b * 256 + t;
    if (node < NN) {
        rowse[node] = make_int2(start, pv);
        dis[node] = rsqrtf(1.0f + degf[t]);
    }
}

// ---------------- GEMM: A' = (act(X) @ W) * dis[row], fp16 out ----------------
// Row-major staging (no transpose), 4 rows x 4 cols per thread, k in chunks of 4.
// __launch_bounds__(256,4) caps VGPR at 128 -> 4 blocks/CU (LDS-limited).
template<bool ACT>
__global__ __launch_bounds__(256, 4) void gemm_k(
    const float* __restrict__ X, const float* __restrict__ W,
    const float* __restrict__ bias_prev, const float* __restrict__ dis,
    __half* __restrict__ Ah)
{
    __shared__ float Ws[64][64];   // [k][j], staged contiguous
    __shared__ float Xs[64][68];   // [r][k], +4 pad: row stride 272 B (16B-aligned, 2-way banks)
    const int t = threadIdx.x;
    const int row0 = blockIdx.x * 64;

    #pragma unroll
    for (int s = t; s < 64 * 64; s += 256) ((float*)Ws)[s] = W[s];
    #pragma unroll
    for (int s = t; s < 64 * 64; s += 256) {
        int r = s >> 6, k = s & 63;
        int row = row0 + r;
        if (row >= NN) row = NN - 1;   // clamp (tail block)
        float v = X[(size_t)row * DD + k];
        if (ACT) v = fmaxf(v + bias_prev[k], 0.0f);
        Xs[r][k] = v;
    }
    __syncthreads();

    const int tc = t & 15;   // cols 4*tc .. 4*tc+3
    const int tr = t >> 4;   // rows 4*tr .. 4*tr+3
    float4 acc[4];
    #pragma unroll
    for (int i = 0; i < 4; ++i) acc[i] = make_float4(0.f, 0.f, 0.f, 0.f);

    #pragma unroll 2
    for (int kc = 0; kc < 16; ++kc) {
        const int k = kc * 4;
        float4 w0 = *reinterpret_cast<const float4*>(&Ws[k + 0][tc * 4]);
        float4 w1 = *reinterpret_cast<const float4*>(&Ws[k + 1][tc * 4]);
        float4 w2 = *reinterpret_cast<const float4*>(&Ws[k + 2][tc * 4]);
        float4 w3 = *reinterpret_cast<const float4*>(&Ws[k + 3][tc * 4]);
        #pragma unroll
        for (int i = 0; i < 4; ++i) {
            float4 xv = *reinterpret_cast<const float4*>(&Xs[tr * 4 + i][k]);
            acc[i].x += xv.x * w0.x + xv.y * w1.x + xv.z * w2.x + xv.w * w3.x;
            acc[i].y += xv.x * w0.y + xv.y * w1.y + xv.z * w2.y + xv.w * w3.y;
            acc[i].z += xv.x * w0.z + xv.y * w1.z + xv.z * w2.z + xv.w * w3.z;
            acc[i].w += xv.x * w0.w + xv.y * w1.w + xv.z * w2.w + xv.w * w3.w;
        }
    }

    #pragma unroll
    for (int i = 0; i < 4; ++i) {
        int row = row0 + tr * 4 + i;
        if (row >= NN) break;
        float d = dis[row];
        __half2 h0 = __floats2half2_rn(acc[i].x * d, acc[i].y * d);
        __half2 h1 = __floats2half2_rn(acc[i].z * d, acc[i].w * d);
        uint2 st;
        st.x = *reinterpret_cast<unsigned int*>(&h0);
        st.y = *reinterpret_cast<unsigned int*>(&h1);
        *reinterpret_cast<uint2*>(&Ah[(size_t)row * DD + tc * 4]) = st;
    }
}

// ---------------- gather: B[c] = dis[c] * (A'[c] + sum_e w_e * A'[r_e]) ----------------
// One wave per node, full 64-lane row loads, 8 independent rows in flight per iter.
__global__ __launch_bounds__(256) void gather_k(
    const int2* __restrict__ rowse, const unsigned int* __restrict__ srt,
    const float* __restrict__ dis,
    const __half* __restrict__ Ah, float* __restrict__ B)
{
    const int node = blockIdx.x * 4 + (threadIdx.x >> 6);
    const int lane = threadIdx.x & 63;
    if (node >= NN) return;
    const int2 se = rowse[node];
    float acc0 = __half2float(Ah[(size_t)node * DD + lane]);  // self-loop term
    float acc1 = 0.0f, acc2 = 0.0f, acc3 = 0.0f;
    const unsigned int* p = srt + se.x;
    uint4 u0 = *reinterpret_cast<const uint4*>(p);
    uint4 u1 = *reinterpret_cast<const uint4*>(p + 4);
    for (int n = se.y; n > 0; n -= 8) {
        uint4 n0, n1;
        if (n > 8) {
            p += 8;
            n0 = *reinterpret_cast<const uint4*>(p);
            n1 = *reinterpret_cast<const uint4*>(p + 4);
        }
        __half h0 = Ah[(size_t)(u0.x & 0xffffu) * DD + lane];
        __half h1 = Ah[(size_t)(u0.y & 0xffffu) * DD + lane];
        __half h2 = Ah[(size_t)(u0.z & 0xffffu) * DD + lane];
        __half h3 = Ah[(size_t)(u0.w & 0xffffu) * DD + lane];
        __half h4 = Ah[(size_t)(u1.x & 0xffffu) * DD + lane];
        __half h5 = Ah[(size_t)(u1.y & 0xffffu) * DD + lane];
        __half h6 = Ah[(size_t)(u1.z & 0xffffu) * DD + lane];
        __half h7 = Ah[(size_t)(u1.w & 0xffffu) * DD + lane];
        acc0 += __half2float(__ushort_as_half((unsigned short)(u0.x >> 16))) * __half2float(h0);
        acc1 += __half2float(__ushort_as_half((unsigned short)(u0.y >> 16))) * __half2float(h1);
        acc2 += __half2float(__ushort_as_half((unsigned short)(u0.z >> 16))) * __half2float(h2);
        acc3 += __half2float(__ushort_as_half((unsigned short)(u0.w >> 16))) * __half2float(h3);
        acc0 += __half2float(__ushort_as_half((unsigned short)(u1.x >> 16))) * __half2float(h4);
        acc1 += __half2float(__ushort_as_half((unsigned short)(u1.y >> 16))) * __half2float(h5);
        acc2 += __half2float(__ushort_as_half((unsigned short)(u1.z >> 16))) * __half2float(h6);
        acc3 += __half2float(__ushort_as_half((unsigned short)(u1.w >> 16))) * __half2float(h7);
        u0 = n0; u1 = n1;
    }
    B[(size_t)node * DD + lane] = dis[node] * ((acc0 + acc1) + (acc2 + acc3));
}

// ---------------- pooling: 32 rows per block ----------------
__global__ __launch_bounds__(64) void pool(
    const float* __restrict__ B, const float* __restrict__ b2,
    const int* __restrict__ batch,
    float* __restrict__ sums, float* __restrict__ cnts, int n)
{
    const int lane = threadIdx.x;
    const int start = blockIdx.x * 32;
    const int end = min(start + 32, n);
    const float bb = b2[lane];
    float acc = 0.0f;
    int cn = 0;
    int curg = batch[start];
    for (int i = start; i < end; ++i) {
        int g = batch[i];
        if (g != curg) {
            unsafeAtomicAdd(&sums[curg * DD + lane], acc);
            if (lane == 0) unsafeAtomicAdd(&cnts[curg], (float)cn);
            acc = 0.0f; cn = 0; curg = g;
        }
        acc += fmaxf(B[(size_t)i * DD + lane] + bb, 0.0f);
        cn++;
    }
    if (cn > 0) {
        unsafeAtomicAdd(&sums[curg * DD + lane], acc);
        if (lane == 0) unsafeAtomicAdd(&cnts[curg], (float)cn);
    }
}

__global__ void finalize(const float* __restrict__ sums, const float* __restrict__ cnts,
                         float* __restrict__ out) {
    int i = blockIdx.x * blockDim.x + threadIdx.x;
    if (i < NG * DD) {
        int g = i >> 6;
        out[i] = sums[i] / fmaxf(cnts[g], 1.0f);
    }
}

// ---------------- host ----------------
extern "C" void kernel_launch(void* const* d_in, const int* in_sizes, int n_in,
                              void* d_out, int out_size, void* d_ws, size_t ws_size,
                              hipStream_t stream) {
    const float* x   = (const float*)d_in[0];
    const int*   ei  = (const int*)  d_in[1];
    const float* ew  = (const float*)d_in[2];
    const int*   bat = (const int*)  d_in[3];
    const float* W1  = (const float*)d_in[4];
    const float* b1  = (const float*)d_in[5];
    const float* W2  = (const float*)d_in[6];
    const float* b2  = (const float*)d_in[7];
    float* out = (float*)d_out;

    char* ws = (char*)d_ws;
    size_t off = 0;
    __half* Ah        = (__half*)(ws + off); off += (size_t)NN * DD * 2;          // 6.4 MB
    float*  B         = (float*) (ws + off); off += (size_t)NN * DD * 4;          // 12.8 MB
    unsigned int* srt = (unsigned int*)(ws + off); off += (size_t)NBKT * SRTB * 4; // 5.6 MB
    unsigned int* tmp_pay = (unsigned int*)(ws + off); off += (size_t)NBKT * MAXB * 4;  // 4.0 MB
    unsigned char* tmp_c8 = (unsigned char*)(ws + off); off += (size_t)NBKT * MAXB;     // 1.0 MB
    int2*   rowse      = (int2*)(ws + off); off += (size_t)NN * 8;
    float*  dis        = (float*)(ws + off); off += (size_t)NN * 4;
    // contiguous zero-init region: bucket_cnt | sums | cnts
    int*    bucket_cnt = (int*)  (ws + off); off += (size_t)NBKT * 4;
    float*  sums       = (float*)(ws + off); off += (size_t)NG * DD * 4;
    float*  cnts       = (float*)(ws + off); off += (size_t)NG * 4;

    (void)hipMemsetAsync(bucket_cnt, 0, (size_t)(NBKT + NG * DD + NG) * 4, stream);

    // CSR build (shared by both layers) — no per-edge global atomics
    bin_k<<<P1NB, 256, 0, stream>>>(ei, ew, bucket_cnt, tmp_pay, tmp_c8);
    build_k<<<NBKT, 256, 0, stream>>>(bucket_cnt, tmp_pay, tmp_c8, srt, rowse, dis);

    // layer 1
    gemm_k<false><<<(NN + 63) / 64, 256, 0, stream>>>(x, W1, nullptr, dis, Ah);
    gather_k<<<(NN + 3) / 4, 256, 0, stream>>>(rowse, srt, dis, Ah, B);

    // layer 2
    gemm_k<true><<<(NN + 63) / 64, 256, 0, stream>>>(B, W2, b1, dis, Ah);
    gather_k<<<(NN + 3) / 4, 256, 0, stream>>>(rowse, srt, dis, Ah, B);

    // pooling (bias+relu fused on read)
    pool<<<(NN + 31) / 32, 64, 0, stream>>>(B, b2, bat, sums, cnts, NN);
    finalize<<<(NG * DD + 255) / 256, 256, 0, stream>>>(sums, cnts, out);
}